// Round 3
// baseline (1649.784 us; speedup 1.0000x reference)
//
#include <hip/hip_runtime.h>
#include <hip/hip_cooperative_groups.h>

namespace cg = cooperative_groups;

typedef __attribute__((ext_vector_type(8))) short bf16x8;
typedef __attribute__((ext_vector_type(4))) float f32x4;

static __device__ __forceinline__ unsigned short f2bf(float x) {
  union { float f; unsigned u; } c; c.f = x;
  unsigned r = c.u + 0x7fffu + ((c.u >> 16) & 1u);
  return (unsigned short)(r >> 16);
}

constexpr int NBLK = 1024;
constexpr int NTHR = 256;
constexpr int SPLITS = 16;
constexpr int KCH = 8192 / SPLITS;   // 512
constexpr int NSTEP = KCH / 32;      // 16

// ---------- device pieces, shared by fused & fallback paths ----------

// Phase 0a: G1t[n][m] = (X @ W1.T)^T  (block handles 8 rows)
static __device__ __forceinline__ void dev_g1(const float* __restrict__ X,
                                              const float* __restrict__ W1,
                                              unsigned short* __restrict__ G1t,
                                              int bid, int t) {
  const int m0 = bid * 8;
  const int row = t >> 5, n = t & 31;
  const float* xr = X + (size_t)(m0 + row) * 32;
  const float* wr = W1 + n * 32;
  float acc = 0.f;
#pragma unroll
  for (int k = 0; k < 32; ++k) acc += xr[k] * wr[k];
  G1t[(size_t)n * 8192 + m0 + row] = f2bf(acc);
}

// Phase 0b: convert A fp32 -> bf16 (grid-strided)
static __device__ __forceinline__ void dev_convert(const float* __restrict__ A,
                                                   unsigned short* __restrict__ Abf,
                                                   int bid, int t) {
  const float4* A4 = (const float4*)A;
  ushort4* O4 = (ushort4*)Abf;
  const int n4 = 8192 * 8192 / 4;  // 16,777,216
#pragma unroll 4
  for (int i = bid * NTHR + t; i < n4; i += NBLK * NTHR) {
    float4 v = A4[i];
    ushort4 o;
    o.x = f2bf(v.x); o.y = f2bf(v.y); o.z = f2bf(v.z); o.w = f2bf(v.w);
    O4[i] = o;
  }
}

// Per-wave GEMM task: 32 rows, full D cols, K-chunk of 512.
// Fragments direct to registers in MFMA layout (lane: row=lane&15, slot=lane>>4).
// NBUF-deep rotating prefetch, fully unrolled -> static reg indices + counted vmcnt.
template <int D, int NBUF>
static __device__ __forceinline__ void gemm_task(const unsigned short* __restrict__ Abf,
                                                 const unsigned short* __restrict__ Gt,
                                                 float* __restrict__ P,
                                                 int gwave, int lane) {
  constexpr int NT = D / 16;
  const int lr = lane & 15, lk = lane >> 4;
  const int m0 = (gwave >> 4) * 32;
  const int ks = gwave & 15;
  const int kb = ks * KCH;

  const unsigned short* a0 = Abf + (size_t)(m0 + lr) * 8192 + kb + lk * 8;
  const unsigned short* a1 = a0 + (size_t)16 * 8192;
  const unsigned short* g[NT];
#pragma unroll
  for (int i = 0; i < NT; ++i)
    g[i] = Gt + (size_t)(i * 16 + lr) * 8192 + kb + lk * 8;

  f32x4 acc[2][NT];
#pragma unroll
  for (int f = 0; f < 2; ++f)
#pragma unroll
    for (int i = 0; i < NT; ++i) acc[f][i] = (f32x4){0.f, 0.f, 0.f, 0.f};

  bf16x8 ab[NBUF][2];
  bf16x8 gb[NBUF][NT];

#pragma unroll
  for (int s = 0; s < NBUF; ++s) {
    ab[s][0] = *(const bf16x8*)(a0 + (size_t)s * 32);
    ab[s][1] = *(const bf16x8*)(a1 + (size_t)s * 32);
#pragma unroll
    for (int i = 0; i < NT; ++i) gb[s][i] = *(const bf16x8*)(g[i] + (size_t)s * 32);
  }

#pragma unroll
  for (int s = 0; s < NSTEP; ++s) {
    const int b = s % NBUF;
#pragma unroll
    for (int i = 0; i < NT; ++i) {
      acc[0][i] = __builtin_amdgcn_mfma_f32_16x16x32_bf16(ab[b][0], gb[b][i], acc[0][i], 0, 0, 0);
      acc[1][i] = __builtin_amdgcn_mfma_f32_16x16x32_bf16(ab[b][1], gb[b][i], acc[1][i], 0, 0, 0);
    }
    if (s + NBUF < NSTEP) {
      ab[b][0] = *(const bf16x8*)(a0 + (size_t)(s + NBUF) * 32);
      ab[b][1] = *(const bf16x8*)(a1 + (size_t)(s + NBUF) * 32);
#pragma unroll
      for (int i = 0; i < NT; ++i)
        gb[b][i] = *(const bf16x8*)(g[i] + (size_t)(s + NBUF) * 32);
    }
  }

  // C/D layout: col = lane&15, row = (lane>>4)*4 + j (validated rounds 1-2)
  float* pw = P + ((size_t)ks * 8192 + m0) * D;
#pragma unroll
  for (int f = 0; f < 2; ++f)
#pragma unroll
    for (int i = 0; i < NT; ++i)
#pragma unroll
      for (int j = 0; j < 4; ++j)
        pw[(size_t)(f * 16 + lk * 4 + j) * D + i * 16 + lr] = acc[f][i][j];
}

// Epilogue: h = relu(sum_s P[s]); Gt_next[n][m] = bf16(h @ W.T)^T  (block: 8 rows)
template <int D_IN, int D_OUT>
static __device__ __forceinline__ void dev_epilogue(const float* __restrict__ P,
                                                    const float* __restrict__ W,
                                                    unsigned short* __restrict__ Gtn,
                                                    float* __restrict__ hL,
                                                    int bid, int t) {
  const int m0 = bid * 8;
  constexpr int NV = 8 * D_IN / 4;  // float4 slots
  if (t < NV) {
    const int c4 = t % (D_IN / 4), row = t / (D_IN / 4);
    const float* base = P + (size_t)(m0 + row) * D_IN + c4 * 4;
    float4 s = *(const float4*)base;
#pragma unroll
    for (int ks = 1; ks < SPLITS; ++ks) {
      float4 v = *(const float4*)(base + (size_t)ks * 8192 * D_IN);
      s.x += v.x; s.y += v.y; s.z += v.z; s.w += v.w;
    }
    hL[row * D_IN + c4 * 4 + 0] = fmaxf(s.x, 0.f);
    hL[row * D_IN + c4 * 4 + 1] = fmaxf(s.y, 0.f);
    hL[row * D_IN + c4 * 4 + 2] = fmaxf(s.z, 0.f);
    hL[row * D_IN + c4 * 4 + 3] = fmaxf(s.w, 0.f);
  }
  __syncthreads();
  constexpr int NO = D_OUT * 8;
#pragma unroll
  for (int o = t; o < NO; o += NTHR) {
    const int n = o >> 3, row = o & 7;
    const float* wr = W + (size_t)n * D_IN;
    float acc = 0.f;
#pragma unroll
    for (int k = 0; k < D_IN; ++k) acc += hL[row * D_IN + k] * wr[k];
    Gtn[(size_t)n * 8192 + m0 + row] = f2bf(acc);
  }
  __syncthreads();
}

// Final: out = sum_s P[s]  (fp32, [8192][32]; W4 already folded into G4)
static __device__ __forceinline__ void dev_final(const float* __restrict__ P,
                                                 float* __restrict__ out,
                                                 int bid, int t) {
  const int m0 = bid * 8;
  if (t < 64) {
    const int c4 = t % 8, row = t / 8;
    const float* base = P + (size_t)(m0 + row) * 32 + c4 * 4;
    float4 s = *(const float4*)base;
#pragma unroll
    for (int ks = 1; ks < SPLITS; ++ks) {
      float4 v = *(const float4*)(base + (size_t)ks * 8192 * 32);
      s.x += v.x; s.y += v.y; s.z += v.z; s.w += v.w;
    }
    *(float4*)(out + (size_t)(m0 + row) * 32 + c4 * 4) = s;
  }
}

// ---------- fused cooperative kernel ----------
__global__ __launch_bounds__(NTHR, 4) void k_fused(const float* A, const float* X,
                                                   const float* W1, const float* W2,
                                                   const float* W3, const float* W4,
                                                   float* out, unsigned short* Abf,
                                                   unsigned short* Ga, unsigned short* Gb,
                                                   float* P) {
  cg::grid_group grid = cg::this_grid();
  const int t = threadIdx.x, bid = blockIdx.x;
  const int wid = t >> 6, lane = t & 63;
  const int gwave = bid * 4 + wid;
  __shared__ float hL[8 * 64];

  dev_g1(X, W1, Ga, bid, t);
  dev_convert(A, Abf, bid, t);
  grid.sync();
  gemm_task<32, 4>(Abf, Ga, P, gwave, lane);
  grid.sync();
  dev_epilogue<32, 64>(P, W2, Gb, hL, bid, t);
  grid.sync();
  gemm_task<64, 2>(Abf, Gb, P, gwave, lane);
  grid.sync();
  dev_epilogue<64, 64>(P, W3, Ga, hL, bid, t);
  grid.sync();
  gemm_task<64, 2>(Abf, Ga, P, gwave, lane);
  grid.sync();
  dev_epilogue<64, 32>(P, W4, Gb, hL, bid, t);
  grid.sync();
  gemm_task<32, 4>(Abf, Gb, P, gwave, lane);
  grid.sync();
  dev_final(P, out, bid, t);
}

// ---------- fallback (non-cooperative) wrappers ----------
__global__ __launch_bounds__(NTHR) void k_phase0(const float* A, const float* X,
                                                 const float* W1, unsigned short* Abf,
                                                 unsigned short* Ga) {
  dev_g1(X, W1, Ga, blockIdx.x, threadIdx.x);
  dev_convert(A, Abf, blockIdx.x, threadIdx.x);
}
template <int D, int NBUF>
__global__ __launch_bounds__(NTHR) void k_gemm(const unsigned short* Abf,
                                               const unsigned short* Gt, float* P) {
  gemm_task<D, NBUF>(Abf, Gt, P, blockIdx.x * 4 + (threadIdx.x >> 6), threadIdx.x & 63);
}
template <int D_IN, int D_OUT>
__global__ __launch_bounds__(NTHR) void k_epi(const float* P, const float* W,
                                              unsigned short* Gtn) {
  __shared__ float hL[8 * 64];
  dev_epilogue<D_IN, D_OUT>(P, W, Gtn, hL, blockIdx.x, threadIdx.x);
}
__global__ __launch_bounds__(NTHR) void k_fin(const float* P, float* out) {
  dev_final(P, out, blockIdx.x, threadIdx.x);
}

extern "C" void kernel_launch(void* const* d_in, const int* in_sizes, int n_in,
                              void* d_out, int out_size, void* d_ws, size_t ws_size,
                              hipStream_t stream) {
  const float* A = (const float*)d_in[0];
  const float* X = (const float*)d_in[1];
  const float* W1 = (const float*)d_in[2];
  const float* W2 = (const float*)d_in[3];
  const float* W3 = (const float*)d_in[4];
  const float* W4 = (const float*)d_in[5];
  float* out = (float*)d_out;

  const size_t ABF_OFF = 0;                           // 134217728 B
  const size_t GA_OFF = 134217728;                    // 1 MB
  const size_t GB_OFF = GA_OFF + 1048576;
  const size_t P_OFF = GB_OFF + 1048576;              // 16*8192*64*4 = 32 MB
  const size_t NEEDED = P_OFF + (size_t)SPLITS * 8192 * 64 * 4;
  if (ws_size < NEEDED) return;

  char* ws = (char*)d_ws;
  unsigned short* Abf = (unsigned short*)(ws + ABF_OFF);
  unsigned short* Ga = (unsigned short*)(ws + GA_OFF);
  unsigned short* Gb = (unsigned short*)(ws + GB_OFF);
  float* P = (float*)(ws + P_OFF);

  void* kargs[] = {(void*)&A, (void*)&X, (void*)&W1, (void*)&W2, (void*)&W3,
                   (void*)&W4, (void*)&out, (void*)&Abf, (void*)&Ga, (void*)&Gb,
                   (void*)&P};
  hipError_t e = hipLaunchCooperativeKernel((const void*)k_fused, dim3(NBLK),
                                            dim3(NTHR), kargs, 0, stream);
  if (e != hipSuccess) {
    // Fallback: same math as separate dispatches.
    k_phase0<<<NBLK, NTHR, 0, stream>>>(A, X, W1, Abf, Ga);
    k_gemm<32, 4><<<NBLK, NTHR, 0, stream>>>(Abf, Ga, P);
    k_epi<32, 64><<<NBLK, NTHR, 0, stream>>>(P, W2, Gb);
    k_gemm<64, 2><<<NBLK, NTHR, 0, stream>>>(Abf, Gb, P);
    k_epi<64, 64><<<NBLK, NTHR, 0, stream>>>(P, W3, Ga);
    k_gemm<64, 2><<<NBLK, NTHR, 0, stream>>>(Abf, Ga, P);
    k_epi<64, 32><<<NBLK, NTHR, 0, stream>>>(P, W4, Gb);
    k_gemm<32, 4><<<NBLK, NTHR, 0, stream>>>(Abf, Gb, P);
    k_fin<<<NBLK, NTHR, 0, stream>>>(P, out);
  }
}